// Round 5
// baseline (1346.026 us; speedup 1.0000x reference)
//
#include <hip/hip_runtime.h>
#include <cstdint>

#define DIVUP(a,b) (((a)+(b)-1)/(b))

typedef __attribute__((ext_vector_type(4))) float f32x4;
typedef __attribute__((ext_vector_type(8))) _Float16 half8;

__device__ __forceinline__ float cubicw(float x) {
  // PyTorch bicubic kernel, a = -0.75
  float ax = fabsf(x);
  float ax2 = ax * ax;
  float ax3 = ax2 * ax;
  if (ax <= 1.0f) return 1.25f * ax3 - 2.25f * ax2 + 1.0f;
  if (ax < 2.0f)  return -0.75f * ax3 + 3.75f * ax2 - 6.0f * ax + 3.0f;
  return 0.0f;
}

// S[b,pix] = sum_c x[b,c,pix]^2
__global__ void sumsq_kernel(const float* __restrict__ x, float* __restrict__ S,
                             int C, int HW, int total) {
  int i = blockIdx.x * blockDim.x + threadIdx.x;
  if (i >= total) return;
  int pix = i % HW, b = i / HW;
  const float* p = x + (size_t)b * C * HW + pix;
  float s = 0.f;
  for (int c = 0; c < C; ++c) { float v = p[(size_t)c * HW]; s += v * v; }
  S[i] = s;
}

// invn[b,p] = 1 / max(sqrt(3x3 zero-padded window sum of S), 1e-12)
__global__ void invnorm_kernel(const float* __restrict__ S, float* __restrict__ invn,
                               int H, int W, int total) {
  int i = blockIdx.x * blockDim.x + threadIdx.x;
  if (i >= total) return;
  int p = i % (H * W), b = i / (H * W);
  int ph = p / W, pw = p % W;
  const float* Sb = S + (size_t)b * H * W;
  float s = 0.f;
  for (int ki = 0; ki < 3; ++ki) {
    int y = ph + ki - 1;
    if (y < 0 || y >= H) continue;
    for (int kj = 0; kj < 3; ++kj) {
      int xx = pw + kj - 1;
      if (xx < 0 || xx >= W) continue;
      s += Sb[y * W + xx];
    }
  }
  float n = fmaxf(sqrtf(s), 1e-12f);
  invn[i] = 1.0f / n;
}

// Split-f16 descriptors, pixel-major [B][HW][C*9]:
// hi = f16(v), lo = f16((v-hi)*4096)  (scaled to stay f16-normal)
__global__ void desc_split_kernel(const float* __restrict__ x, const float* __restrict__ invn,
                                  _Float16* __restrict__ hi, _Float16* __restrict__ lo,
                                  int C, int H, int W, int total) {
  int i = blockIdx.x * blockDim.x + threadIdx.x;
  if (i >= total) return;
  int c = i % C;
  int p = (i / C) % (H * W);
  int b = i / (C * H * W);
  int ph = p / W, pw = p % W;
  float s = invn[b * H * W + p];
  size_t obase = ((size_t)b * H * W + p) * (size_t)(C * 9) + (size_t)c * 9;
  const float* xb = x + (size_t)(b * C + c) * H * W;
#pragma unroll
  for (int r = 0; r < 9; ++r) {
    int y = ph + r / 3 - 1, xx = pw + r % 3 - 1;
    float v = 0.f;
    if (y >= 0 && y < H && xx >= 0 && xx < W) v = xb[y * W + xx] * s;
    _Float16 h = (_Float16)v;
    float hf = (float)h;
    _Float16 l = (_Float16)((v - hf) * 4096.0f);
    hi[obase + r] = h;
    lo[obase + r] = l;
  }
}

// Axis-1 bicubic upsample to 4096 rows
__global__ void upsample_n_kernel(const float* __restrict__ Rin, float* __restrict__ out,
                                  int Nin, int cols, float invscale, int total) {
  int i = blockIdx.x * blockDim.x + threadIdx.x;
  if (i >= total) return;
  int j = i % cols;
  int n = (i / cols) & 4095;
  int b = i / (cols * 4096);
  float src = (n + 0.5f) * invscale - 0.5f;
  float f = floorf(src);
  float tt = src - f;
  int fi = (int)f;
  const float* Rb = Rin + (size_t)b * Nin * cols;
  float s = 0.f;
#pragma unroll
  for (int tp = 0; tp < 4; ++tp) {
    int ii = min(max(fi + tp - 1, 0), Nin - 1);
    s += cubicw(tt - (float)(tp - 1)) * Rb[(size_t)ii * cols + j];
  }
  out[i] = s;
}

__global__ void init_packed_kernel(unsigned long long* __restrict__ p, int n) {
  int i = blockIdx.x * blockDim.x + threadIdx.x;
  if (i < n) p[i] = 0ull;
}

// Split-f16 MFMA GEMM: R[n,m] = sum_d A[n][d]*B[m][d], A/B row-major [rows][K].
// Block tile 128 (A rows) x 64 (B rows), 4 waves of 64x32 (4x2 of 16x16x32).
// Accumulators: S1 (hi*hi) + S2 ((hi*lo + lo*hi), scaled 2^-12) = 64 regs.
// FUSED: adds axis-2 bicubic taps of up2/up1, /3, packed max/argmax over rows.
template<bool FUSED>
__global__ __launch_bounds__(256, 2)
void mfma_gemm_kernel(const _Float16* __restrict__ Ahi, const _Float16* __restrict__ Alo,
                      const _Float16* __restrict__ Bhi, const _Float16* __restrict__ Blo,
                      int M, int N, int K, float* __restrict__ C,
                      const float* __restrict__ up2, const float* __restrict__ up1,
                      unsigned long long* __restrict__ packed) {
  const int LD = 44;                       // LDS row stride in halves (88 B)
  int b = blockIdx.z;
  int row0 = blockIdx.y * 128;             // A rows (ref axis when fused)
  int col0 = blockIdx.x * 64;              // B rows (lr axis when fused)
  int t = threadIdx.x;
  int lane = t & 63, wave = t >> 6;
  int wy = wave & 1, wx = wave >> 1;       // wave tile: rows wy*64, cols wx*32
  int quad = lane >> 4, lm = lane & 15;

  __shared__ _Float16 AsH[128 * LD];
  __shared__ _Float16 AsL[128 * LD];
  __shared__ _Float16 BsH[64 * LD];
  __shared__ _Float16 BsL[64 * LD];

  // A staging: thread -> row t&127, plane t>>7; 4 half8 covering k 0..31
  int arow = t & 127, aplane = t >> 7;
  const _Float16* pA = (aplane ? Alo : Ahi) + ((size_t)b * M + row0 + arow) * (size_t)K;
  _Float16* ldsA = (aplane ? AsL : AsH) + arow * LD;
  // B staging: thread -> row t&63, sel t>>6: plane sel&1, k-offset (sel>>1)*16
  int brow = t & 63, bsel = t >> 6;
  int bplane = bsel & 1, bko = (bsel >> 1) * 16;
  const _Float16* pB = (bplane ? Blo : Bhi) + ((size_t)b * N + col0 + brow) * (size_t)K + bko;
  _Float16* ldsB = (bplane ? BsL : BsH) + brow * LD + bko;

  f32x4 S1[4][2] = {};
  f32x4 S2[4][2] = {};

  half8 a0 = *(const half8*)(pA);
  half8 a1 = *(const half8*)(pA + 8);
  half8 a2 = *(const half8*)(pA + 16);
  half8 a3 = *(const half8*)(pA + 24);
  half8 b0 = *(const half8*)(pB);
  half8 b1 = *(const half8*)(pB + 8);

  for (int k0 = 0; k0 < K; k0 += 32) {
    __syncthreads();
    *(half8*)&ldsA[0]  = a0;
    *(half8*)&ldsA[8]  = a1;
    *(half8*)&ldsA[16] = a2;
    *(half8*)&ldsA[24] = a3;
    *(half8*)&ldsB[0]  = b0;
    *(half8*)&ldsB[8]  = b1;
    __syncthreads();
    if (k0 + 32 < K) {
      a0 = *(const half8*)(pA + k0 + 32);
      a1 = *(const half8*)(pA + k0 + 40);
      a2 = *(const half8*)(pA + k0 + 48);
      a3 = *(const half8*)(pA + k0 + 56);
      b0 = *(const half8*)(pB + k0 + 32);
      b1 = *(const half8*)(pB + k0 + 40);
    }
    half8 aH[4], aL[4], bH[2], bL[2];
#pragma unroll
    for (int i = 0; i < 4; ++i) {
      int ra = (wy * 64 + i * 16 + lm) * LD + quad * 8;
      aH[i] = *(const half8*)&AsH[ra];
      aL[i] = *(const half8*)&AsL[ra];
    }
#pragma unroll
    for (int j = 0; j < 2; ++j) {
      int rb = (wx * 32 + j * 16 + lm) * LD + quad * 8;
      bH[j] = *(const half8*)&BsH[rb];
      bL[j] = *(const half8*)&BsL[rb];
    }
#pragma unroll
    for (int i = 0; i < 4; ++i)
#pragma unroll
      for (int j = 0; j < 2; ++j) {
        S1[i][j] = __builtin_amdgcn_mfma_f32_16x16x32_f16(aH[i], bH[j], S1[i][j], 0, 0, 0);
        S2[i][j] = __builtin_amdgcn_mfma_f32_16x16x32_f16(aH[i], bL[j], S2[i][j], 0, 0, 0);
        S2[i][j] = __builtin_amdgcn_mfma_f32_16x16x32_f16(aL[i], bH[j], S2[i][j], 0, 0, 0);
      }
  }

  const float inv4096 = 1.0f / 4096.0f;
  if constexpr (!FUSED) {
    float* Cb = C + (size_t)b * M * N;
#pragma unroll
    for (int j = 0; j < 2; ++j) {
      int gm = col0 + wx * 32 + j * 16 + lm;
#pragma unroll
      for (int i = 0; i < 4; ++i)
#pragma unroll
        for (int r = 0; r < 4; ++r) {
          int gn = row0 + wy * 64 + i * 16 + quad * 4 + r;
          Cb[(size_t)gn * N + gm] = S1[i][j][r] + S2[i][j][r] * inv4096;
        }
    }
  } else {
    const float* u2b = up2 + (size_t)b * 4096 * 1024;
    const float* u1b = up1 + (size_t)b * 4096 * 256;
#pragma unroll
    for (int j = 0; j < 2; ++j) {
      int gm = col0 + wx * 32 + j * 16 + lm;
      float src2 = (gm + 0.5f) * 0.25f - 0.5f;
      float f2 = floorf(src2); float t2 = src2 - f2; int i2 = (int)f2;
      int idx2[4]; float w2[4];
#pragma unroll
      for (int tp = 0; tp < 4; ++tp) {
        idx2[tp] = min(max(i2 + tp - 1, 0), 1023);
        w2[tp] = cubicw(t2 - (float)(tp - 1));
      }
      float src1 = (gm + 0.5f) * 0.0625f - 0.5f;
      float f1 = floorf(src1); float t1 = src1 - f1; int i1 = (int)f1;
      int idx1[4]; float w1[4];
#pragma unroll
      for (int tp = 0; tp < 4; ++tp) {
        idx1[tp] = min(max(i1 + tp - 1, 0), 255);
        w1[tp] = cubicw(t1 - (float)(tp - 1));
      }
      unsigned long long best = 0ull;
#pragma unroll
      for (int i = 0; i < 4; ++i) {
#pragma unroll
        for (int r = 0; r < 4; ++r) {
          int gn = row0 + wy * 64 + i * 16 + quad * 4 + r;
          float v = S1[i][j][r] + S2[i][j][r] * inv4096;
          const float* r2row = u2b + (size_t)gn * 1024;
          const float* r1row = u1b + (size_t)gn * 256;
          v += w2[0] * r2row[idx2[0]] + w2[1] * r2row[idx2[1]]
             + w2[2] * r2row[idx2[2]] + w2[3] * r2row[idx2[3]];
          v += w1[0] * r1row[idx1[0]] + w1[1] * r1row[idx1[1]]
             + w1[2] * r1row[idx1[2]] + w1[3] * r1row[idx1[3]];
          v *= (1.0f / 3.0f);
          unsigned int fb = __float_as_uint(v);
          unsigned int key = (fb & 0x80000000u) ? ~fb : (fb | 0x80000000u);
          unsigned long long pk = ((unsigned long long)key << 32)
                                | (unsigned long long)(0xFFFFFFFFu - (unsigned)gn);
          best = best > pk ? best : pk;
        }
      }
      unsigned long long o;
      o = __shfl_xor(best, 16); best = best > o ? best : o;
      o = __shfl_xor(best, 32); best = best > o ? best : o;
      if (lane < 16) atomicMax(&packed[(size_t)b * 4096 + gm], best);
    }
  }
}

__global__ void finalize_kernel(const unsigned long long* __restrict__ packed,
                                float* __restrict__ s3_out, int* __restrict__ arg, int total) {
  int i = blockIdx.x * blockDim.x + threadIdx.x;
  if (i >= total) return;
  unsigned long long pk = packed[i];
  unsigned int key = (unsigned int)(pk >> 32);
  unsigned int fb = (key & 0x80000000u) ? (key ^ 0x80000000u) : ~key;
  s3_out[i] = __uint_as_float(fb);
  arg[i] = (int)(0xFFFFFFFFu - (unsigned int)(pk & 0xFFFFFFFFull));
}

// fold(gather(unfold(ref, KK,PP,SS), arg)) / 9 — pure gather, <=9 taps/output.
template<int KK, int SS, int PP>
__global__ void fold_gather_kernel(const float* __restrict__ ref, const int* __restrict__ arg,
                                   float* __restrict__ out, int C, int H, int W, int total) {
  int i = blockIdx.x * blockDim.x + threadIdx.x;
  if (i >= total) return;
  int w = i % W;
  int h = (i / W) % H;
  int c = (i / (W * H)) % C;
  int b = i / (W * H * C);
  int y = h + PP, x = w + PP;
  int ho_lo = (y - KK + 1) > 0 ? (y - KK + 1 + SS - 1) / SS : 0;
  int ho_hi = min(63, y / SS);
  int wo_lo = (x - KK + 1) > 0 ? (x - KK + 1 + SS - 1) / SS : 0;
  int wo_hi = min(63, x / SS);
  const int* argb = arg + b * 4096;
  const float* refb = ref + (size_t)(b * C + c) * H * W;
  float acc = 0.f;
  for (int ho = ho_lo; ho <= ho_hi; ++ho) {
    int ki = y - SS * ho;
    for (int wo = wo_lo; wo <= wo_hi; ++wo) {
      int kj = x - SS * wo;
      int q = argb[(ho << 6) + wo];
      int qh = q >> 6, qw = q & 63;
      int ry = SS * qh + ki - PP;
      int rx = SS * qw + kj - PP;
      if (ry >= 0 && ry < H && rx >= 0 && rx < W) acc += refb[ry * W + rx];
    }
  }
  out[i] = acc * (1.0f / 9.0f);
}

extern "C" void kernel_launch(void* const* d_in, const int* in_sizes, int n_in,
                              void* d_out, int out_size, void* d_ws, size_t ws_size,
                              hipStream_t stream) {
  const float* lrsr1 = (const float*)d_in[0];
  const float* lrsr2 = (const float*)d_in[1];
  const float* lrsr3 = (const float*)d_in[2];
  const float* refsr1 = (const float*)d_in[3];
  const float* refsr2 = (const float*)d_in[4];
  const float* refsr3 = (const float*)d_in[5];
  const float* ref1 = (const float*)d_in[6];
  const float* ref2 = (const float*)d_in[7];
  const float* ref3 = (const float*)d_in[8];
  float* out = (float*)d_out;
  float* ws = (float*)d_ws;

  const int B = 2;
  // split-f16 descriptor planes (halves), all pixel-major [B][HW][C*9]
  const size_t P3 = (size_t)B * 4096 * 576;   // lv3 plane halves
  const size_t P2 = (size_t)B * 1024 * 1152;  // lv2
  const size_t P1 = (size_t)B * 256 * 2304;   // lv1
  size_t off = 0;
  _Float16* r3hi = (_Float16*)(ws + off);
  _Float16* r3lo = r3hi + P3;
  _Float16* l3hi = r3lo + P3;
  _Float16* l3lo = l3hi + P3;
  off += (4 * P3) / 2;
  _Float16* r2hi = (_Float16*)(ws + off);
  _Float16* r2lo = r2hi + P2;
  _Float16* l2hi = r2lo + P2;
  _Float16* l2lo = l2hi + P2;
  off += (4 * P2) / 2;
  _Float16* r1hi = (_Float16*)(ws + off);
  _Float16* r1lo = r1hi + P1;
  _Float16* l1hi = r1lo + P1;
  _Float16* l1lo = l1hi + P1;
  off += (4 * P1) / 2;
  size_t off_R2  = off;                        // [2,1024,1024] f32
  size_t off_R1  = off_R2 + (size_t)B * 1024 * 1024;  // [2,256,256]
  size_t off_up2 = off_R1 + (size_t)B * 256 * 256;    // [2,4096,1024]
  size_t off_up1 = off_up2 + (size_t)B * 4096 * 1024; // [2,4096,256]
  size_t off_S   = off_up1 + (size_t)B * 4096 * 256;  // [2,HWmax]
  size_t off_invn= off_S   + (size_t)B * 4096;
  size_t off_pk  = off_invn+ (size_t)B * 4096;        // [2,4096] u64
  size_t off_arg = off_pk  + (size_t)B * 4096 * 2;    // [2,4096] int

  auto run_split = [&](const float* x, int C, int H, int W, _Float16* hi, _Float16* lo) {
    int HW = H * W;
    int tS = B * HW;
    sumsq_kernel<<<DIVUP(tS, 256), 256, 0, stream>>>(x, ws + off_S, C, HW, tS);
    invnorm_kernel<<<DIVUP(tS, 256), 256, 0, stream>>>(ws + off_S, ws + off_invn, H, W, tS);
    int tD = B * C * HW;
    desc_split_kernel<<<DIVUP(tD, 256), 256, 0, stream>>>(x, ws + off_invn, hi, lo, C, H, W, tD);
  };

  run_split(refsr3, 64, 64, 64, r3hi, r3lo);
  run_split(lrsr3, 64, 64, 64, l3hi, l3lo);
  run_split(refsr2, 128, 32, 32, r2hi, r2lo);
  run_split(lrsr2, 128, 32, 32, l2hi, l2lo);
  run_split(refsr1, 256, 16, 16, r1hi, r1lo);
  run_split(lrsr1, 256, 16, 16, l1hi, l1lo);

  // small correlation GEMMs R2, R1 (split-f16 MFMA, unfused)
  {
    dim3 g(1024 / 64, 1024 / 128, B);
    mfma_gemm_kernel<false><<<g, 256, 0, stream>>>(r2hi, r2lo, l2hi, l2lo,
                                                   1024, 1024, 1152, ws + off_R2,
                                                   nullptr, nullptr, nullptr);
  }
  {
    dim3 g(256 / 64, 256 / 128, B);
    mfma_gemm_kernel<false><<<g, 256, 0, stream>>>(r1hi, r1lo, l1hi, l1lo,
                                                   256, 256, 2304, ws + off_R1,
                                                   nullptr, nullptr, nullptr);
  }

  // axis-1 bicubic upsample of R2 (x4) and R1 (x16) to 4096 rows
  {
    int tU2 = B * 4096 * 1024;
    upsample_n_kernel<<<DIVUP(tU2, 256), 256, 0, stream>>>(ws + off_R2, ws + off_up2,
                                                           1024, 1024, 0.25f, tU2);
    int tU1 = B * 4096 * 256;
    upsample_n_kernel<<<DIVUP(tU1, 256), 256, 0, stream>>>(ws + off_R1, ws + off_up1,
                                                           256, 256, 0.0625f, tU1);
  }

  unsigned long long* pk = (unsigned long long*)(ws + off_pk);
  init_packed_kernel<<<DIVUP(B * 4096, 256), 256, 0, stream>>>(pk, B * 4096);

  // fused R3 MFMA GEMM + bicubic add + max/argmax
  {
    dim3 g(4096 / 64, 4096 / 128, B);
    mfma_gemm_kernel<true><<<g, 256, 0, stream>>>(r3hi, r3lo, l3hi, l3lo,
                                                  4096, 4096, 576, nullptr,
                                                  ws + off_up2, ws + off_up1, pk);
  }

  int* argp = (int*)(ws + off_arg);
  finalize_kernel<<<DIVUP(B * 4096, 256), 256, 0, stream>>>(pk, out, argp, B * 4096);

  // transfer: fold(gather(unfold(ref_lvX)))/9
  float* T3 = out + 8192;
  float* T2 = T3 + (size_t)B * 256 * 64 * 64;
  float* T1 = T2 + (size_t)B * 128 * 128 * 128;
  {
    int tt = B * 256 * 64 * 64;
    fold_gather_kernel<3, 1, 1><<<DIVUP(tt, 256), 256, 0, stream>>>(ref3, argp, T3, 256, 64, 64, tt);
  }
  {
    int tt = B * 128 * 128 * 128;
    fold_gather_kernel<6, 2, 2><<<DIVUP(tt, 256), 256, 0, stream>>>(ref2, argp, T2, 128, 128, 128, tt);
  }
  {
    int tt = B * 64 * 256 * 256;
    fold_gather_kernel<12, 4, 4><<<DIVUP(tt, 256), 256, 0, stream>>>(ref1, argp, T1, 64, 256, 256, tt);
  }
}